// Round 1
// baseline (2570.062 us; speedup 1.0000x reference)
//
#include <hip/hip_runtime.h>

#define NN 50000
#define NE 800000
#define DIN 96
#define DH 128
#define DOUT 16

// ---------------- scatter layer 1: agg1[dst] += x[src], deg[dst] += 1 ----------------
__global__ __launch_bounds__(256) void k_scatter1(const float* __restrict__ x,
                                                  const int* __restrict__ ei,
                                                  float* __restrict__ agg1,
                                                  float* __restrict__ deg) {
    long long t = (long long)blockIdx.x * blockDim.x + threadIdx.x;
    const long long total = (long long)NE * (DIN / 4);
    if (t >= total) return;
    int e  = (int)(t / (DIN / 4));
    int c4 = (int)(t % (DIN / 4));
    int s = ei[e];
    int d = ei[NE + e];
    if (c4 == 0) atomicAdd(&deg[d], 1.0f);
    const float4 v = ((const float4*)(x + (size_t)s * DIN))[c4];
    float* ap = agg1 + (size_t)d * DIN + c4 * 4;
    atomicAdd(ap + 0, v.x);
    atomicAdd(ap + 1, v.y);
    atomicAdd(ap + 2, v.z);
    atomicAdd(ap + 3, v.w);
}

// ---------------- layer 1 dense: h = relu(agg1/deg @ W1l + b1 + x @ W1r) ----------------
__global__ __launch_bounds__(128) void k_lin1(const float* __restrict__ x,
                                              const float* __restrict__ agg1,
                                              const float* __restrict__ deg,
                                              const float* __restrict__ W1l,
                                              const float* __restrict__ b1,
                                              const float* __restrict__ W1r,
                                              float* __restrict__ h) {
    __shared__ float sx[8][DIN];
    __shared__ float sa[8][DIN];
    __shared__ float sinv[8];
    const int nb = blockIdx.x * 8;
    const int tid = threadIdx.x;
    if (tid < 8) sinv[tid] = 1.0f / fmaxf(deg[nb + tid], 1.0f);
    __syncthreads();
    for (int idx = tid; idx < 8 * DIN; idx += 128) {
        int m = idx / DIN, k = idx % DIN;
        sx[m][k] = x[(size_t)(nb + m) * DIN + k];
        sa[m][k] = agg1[(size_t)(nb + m) * DIN + k] * sinv[m];
    }
    __syncthreads();
    float acc[8];
    const float bj = b1[tid];
#pragma unroll
    for (int m = 0; m < 8; ++m) acc[m] = bj;
    for (int k = 0; k < DIN; ++k) {
        const float wl = W1l[k * DH + tid];
        const float wr = W1r[k * DH + tid];
#pragma unroll
        for (int m = 0; m < 8; ++m) acc[m] += sa[m][k] * wl + sx[m][k] * wr;
    }
#pragma unroll
    for (int m = 0; m < 8; ++m)
        h[(size_t)(nb + m) * DH + tid] = fmaxf(acc[m], 0.0f);
}

// ---------------- scatter layer 2: agg2[dst] += h[src] ----------------
__global__ __launch_bounds__(256) void k_scatter2(const float* __restrict__ h,
                                                  const int* __restrict__ ei,
                                                  float* __restrict__ agg2) {
    long long t = (long long)blockIdx.x * blockDim.x + threadIdx.x;
    const long long total = (long long)NE * (DH / 4);
    if (t >= total) return;
    int e  = (int)(t / (DH / 4));
    int c4 = (int)(t % (DH / 4));
    int s = ei[e];
    int d = ei[NE + e];
    const float4 v = ((const float4*)(h + (size_t)s * DH))[c4];
    float* ap = agg2 + (size_t)d * DH + c4 * 4;
    atomicAdd(ap + 0, v.x);
    atomicAdd(ap + 1, v.y);
    atomicAdd(ap + 2, v.z);
    atomicAdd(ap + 3, v.w);
}

// ---------------- layer 2 dense + softmax ----------------
// one wave per node; lane = oc*4 + kq; kq covers k in [kq*32, kq*32+32)
__global__ __launch_bounds__(256) void k_lin2(const float* __restrict__ h,
                                              const float* __restrict__ agg2,
                                              const float* __restrict__ deg,
                                              const float* __restrict__ W2l,
                                              const float* __restrict__ b2,
                                              const float* __restrict__ W2r,
                                              float* __restrict__ out) {
    __shared__ float sh[4][2 * DH];
    const int wid  = threadIdx.x >> 6;
    const int lane = threadIdx.x & 63;
    const int n = blockIdx.x * 4 + wid;
    const float inv = 1.0f / fmaxf(deg[n], 1.0f);
    if (lane < 32) {
        float4 v = ((const float4*)(h + (size_t)n * DH))[lane];
        ((float4*)&sh[wid][0])[lane] = v;
    } else {
        float4 v = ((const float4*)(agg2 + (size_t)n * DH))[lane - 32];
        v.x *= inv; v.y *= inv; v.z *= inv; v.w *= inv;
        ((float4*)&sh[wid][DH])[lane - 32] = v;
    }
    __syncthreads();
    const int oc = lane >> 2;
    const int kq = lane & 3;
    float acc = 0.0f;
#pragma unroll 4
    for (int i = 0; i < 32; ++i) {
        const int k = kq * 32 + i;
        acc += sh[wid][k] * W2r[k * DOUT + oc];
        acc += sh[wid][DH + k] * W2l[k * DOUT + oc];
    }
    acc += __shfl_xor(acc, 1);
    acc += __shfl_xor(acc, 2);
    acc += b2[oc];
    float mx = acc;
#pragma unroll
    for (int off = 4; off <= 32; off <<= 1) mx = fmaxf(mx, __shfl_xor(mx, off));
    const float ev = expf(acc - mx);
    float ssum = ev;
#pragma unroll
    for (int off = 4; off <= 32; off <<= 1) ssum += __shfl_xor(ssum, off);
    if (kq == 0) out[(size_t)n * DOUT + oc] = ev / ssum;
}

extern "C" void kernel_launch(void* const* d_in, const int* in_sizes, int n_in,
                              void* d_out, int out_size, void* d_ws, size_t ws_size,
                              hipStream_t stream) {
    const float* x   = (const float*)d_in[0];
    const int*   ei  = (const int*)d_in[1];
    const float* W1l = (const float*)d_in[2];
    const float* b1  = (const float*)d_in[3];
    const float* W1r = (const float*)d_in[4];
    const float* W2l = (const float*)d_in[5];
    const float* b2  = (const float*)d_in[6];
    const float* W2r = (const float*)d_in[7];
    float* out = (float*)d_out;

    float* ws   = (float*)d_ws;
    float* deg  = ws;                          // NN
    float* agg1 = deg + NN;                    // NN*DIN
    float* h    = agg1 + (size_t)NN * DIN;     // NN*DH
    float* agg2 = h + (size_t)NN * DH;         // NN*DH

    hipMemsetAsync(deg, 0, (size_t)(NN + (size_t)NN * DIN) * sizeof(float), stream);
    hipMemsetAsync(agg2, 0, (size_t)NN * DH * sizeof(float), stream);

    {
        const long long total = (long long)NE * (DIN / 4);
        const int blocks = (int)((total + 255) / 256);
        k_scatter1<<<blocks, 256, 0, stream>>>(x, ei, agg1, deg);
    }
    k_lin1<<<NN / 8, 128, 0, stream>>>(x, agg1, deg, W1l, b1, W1r, h);
    {
        const long long total = (long long)NE * (DH / 4);
        const int blocks = (int)((total + 255) / 256);
        k_scatter2<<<blocks, 256, 0, stream>>>(h, ei, agg2);
    }
    k_lin2<<<NN / 4, 256, 0, stream>>>(h, agg2, deg, W2l, b2, W2r, out);
}

// Round 2
// 457.237 us; speedup vs baseline: 5.6209x; 5.6209x over previous
//
#include <hip/hip_runtime.h>

#define NN 50000
#define NE 800000
#define DIN 96
#define DH 128
#define DOUT 16

// ---------------- CSR build: histogram, scan, fill ----------------
__global__ __launch_bounds__(256) void k_hist(const int* __restrict__ ei, int* __restrict__ cnt) {
    int e = blockIdx.x * 256 + threadIdx.x;
    if (e < NE) atomicAdd(&cnt[ei[NE + e]], 1);
}

__global__ __launch_bounds__(256) void k_scan(const int* __restrict__ cnt, int* __restrict__ off) {
    __shared__ int buf[256];
    const int per = (NN + 255) / 256;   // 196
    const int tid = threadIdx.x;
    const int b = tid * per;
    const int e = min(b + per, NN);
    int s = 0;
    for (int i = b; i < e; ++i) s += cnt[i];
    buf[tid] = s;
    __syncthreads();
    for (int o = 1; o < 256; o <<= 1) {
        int t = (tid >= o) ? buf[tid - o] : 0;
        __syncthreads();
        buf[tid] += t;
        __syncthreads();
    }
    int run = buf[tid] - s;             // exclusive prefix of this thread's chunk
    for (int i = b; i < e; ++i) { off[i] = run; run += cnt[i]; }
    if (tid == 255) off[NN] = NE;
}

__global__ __launch_bounds__(256) void k_fill(const int* __restrict__ ei, const int* __restrict__ off,
                                              int* __restrict__ cur, int* __restrict__ csr) {
    int e = blockIdx.x * 256 + threadIdx.x;
    if (e < NE) {
        int d = ei[NE + e];
        int p = atomicAdd(&cur[d], 1);
        csr[off[d] + p] = ei[e];
    }
}

// ---------------- gather mean-aggregate: mean[n] = (1/deg) * sum_{s in N(n)} feat[s] ----------------
template <int D4>
__global__ __launch_bounds__(256) void k_agg(const float* __restrict__ feat,
                                             const int* __restrict__ csr,
                                             const int* __restrict__ off,
                                             float* __restrict__ mean) {
    const int g = threadIdx.x >> 5;     // 8 groups of 32 lanes
    const int l = threadIdx.x & 31;
    const int n = blockIdx.x * 8 + g;
    if (n >= NN || l >= D4) return;
    const int b = off[n], e = off[n + 1];
    const float4* f4 = (const float4*)feat;
    float4 acc = {0.f, 0.f, 0.f, 0.f};
    int i = b;
    for (; i + 1 < e; i += 2) {
        int s0 = csr[i], s1 = csr[i + 1];
        float4 v0 = f4[(size_t)s0 * D4 + l];
        float4 v1 = f4[(size_t)s1 * D4 + l];
        acc.x += v0.x + v1.x; acc.y += v0.y + v1.y;
        acc.z += v0.z + v1.z; acc.w += v0.w + v1.w;
    }
    if (i < e) {
        float4 v = f4[(size_t)csr[i] * D4 + l];
        acc.x += v.x; acc.y += v.y; acc.z += v.z; acc.w += v.w;
    }
    const float inv = (e > b) ? 1.0f / (float)(e - b) : 0.0f;
    acc.x *= inv; acc.y *= inv; acc.z *= inv; acc.w *= inv;
    ((float4*)mean)[(size_t)n * D4 + l] = acc;
}

// ---------------- layer 1 dense: h = relu(mean1 @ W1l + b1 + x @ W1r) ----------------
__global__ __launch_bounds__(128) void k_lin1(const float* __restrict__ x,
                                              const float* __restrict__ mean1,
                                              const float* __restrict__ W1l,
                                              const float* __restrict__ b1,
                                              const float* __restrict__ W1r,
                                              float* __restrict__ h) {
    __shared__ float sx[8][DIN];
    __shared__ float sa[8][DIN];
    const int nb = blockIdx.x * 8;
    const int tid = threadIdx.x;
    for (int idx = tid; idx < 8 * DIN; idx += 128) {
        int m = idx / DIN, k = idx % DIN;
        sx[m][k] = x[(size_t)(nb + m) * DIN + k];
        sa[m][k] = mean1[(size_t)(nb + m) * DIN + k];
    }
    __syncthreads();
    float acc[8];
    const float bj = b1[tid];
#pragma unroll
    for (int m = 0; m < 8; ++m) acc[m] = bj;
    for (int k = 0; k < DIN; ++k) {
        const float wl = W1l[k * DH + tid];
        const float wr = W1r[k * DH + tid];
#pragma unroll
        for (int m = 0; m < 8; ++m) acc[m] += sa[m][k] * wl + sx[m][k] * wr;
    }
#pragma unroll
    for (int m = 0; m < 8; ++m)
        h[(size_t)(nb + m) * DH + tid] = fmaxf(acc[m], 0.0f);
}

// ---------------- layer 2 dense + softmax ----------------
__global__ __launch_bounds__(256) void k_lin2(const float* __restrict__ h,
                                              const float* __restrict__ mean2,
                                              const float* __restrict__ W2l,
                                              const float* __restrict__ b2,
                                              const float* __restrict__ W2r,
                                              float* __restrict__ out) {
    __shared__ float sh[4][2 * DH];
    const int wid  = threadIdx.x >> 6;
    const int lane = threadIdx.x & 63;
    const int n = blockIdx.x * 4 + wid;
    if (lane < 32) {
        float4 v = ((const float4*)(h + (size_t)n * DH))[lane];
        ((float4*)&sh[wid][0])[lane] = v;
    } else {
        float4 v = ((const float4*)(mean2 + (size_t)n * DH))[lane - 32];
        ((float4*)&sh[wid][DH])[lane - 32] = v;
    }
    __syncthreads();
    const int oc = lane >> 2;
    const int kq = lane & 3;
    float acc = 0.0f;
#pragma unroll 4
    for (int i = 0; i < 32; ++i) {
        const int k = kq * 32 + i;
        acc += sh[wid][k] * W2r[k * DOUT + oc];
        acc += sh[wid][DH + k] * W2l[k * DOUT + oc];
    }
    acc += __shfl_xor(acc, 1);
    acc += __shfl_xor(acc, 2);
    acc += b2[oc];
    float mx = acc;
#pragma unroll
    for (int off = 4; off <= 32; off <<= 1) mx = fmaxf(mx, __shfl_xor(mx, off));
    const float ev = expf(acc - mx);
    float ssum = ev;
#pragma unroll
    for (int off = 4; off <= 32; off <<= 1) ssum += __shfl_xor(ssum, off);
    if (kq == 0) out[(size_t)n * DOUT + oc] = ev / ssum;
}

extern "C" void kernel_launch(void* const* d_in, const int* in_sizes, int n_in,
                              void* d_out, int out_size, void* d_ws, size_t ws_size,
                              hipStream_t stream) {
    const float* x   = (const float*)d_in[0];
    const int*   ei  = (const int*)d_in[1];
    const float* W1l = (const float*)d_in[2];
    const float* b1  = (const float*)d_in[3];
    const float* W1r = (const float*)d_in[4];
    const float* W2l = (const float*)d_in[5];
    const float* b2  = (const float*)d_in[6];
    const float* W2r = (const float*)d_in[7];
    float* out = (float*)d_out;

    // workspace layout (ints first, then floats)
    int* cnt = (int*)d_ws;                       // NN
    int* cur = cnt + NN;                         // NN
    int* off = cur + NN;                         // NN + 1
    int* csr = off + NN + 1;                     // NE
    float* mean1 = (float*)(csr + NE);           // NN*DIN
    float* h     = mean1 + (size_t)NN * DIN;     // NN*DH
    float* mean2 = h + (size_t)NN * DH;          // NN*DH

    hipMemsetAsync(cnt, 0, (size_t)2 * NN * sizeof(int), stream);  // cnt + cur

    const int eblocks = (NE + 255) / 256;
    k_hist<<<eblocks, 256, 0, stream>>>(ei, cnt);
    k_scan<<<1, 256, 0, stream>>>(cnt, off);
    k_fill<<<eblocks, 256, 0, stream>>>(ei, off, cur, csr);

    k_agg<DIN / 4><<<NN / 8, 256, 0, stream>>>(x, csr, off, mean1);
    k_lin1<<<NN / 8, 128, 0, stream>>>(x, mean1, W1l, b1, W1r, h);
    k_agg<DH / 4><<<NN / 8, 256, 0, stream>>>(h, csr, off, mean2);
    k_lin2<<<NN / 4, 256, 0, stream>>>(h, mean2, W2l, b2, W2r, out);
}